// Round 4
// baseline (690.617 us; speedup 1.0000x reference)
//
#include <hip/hip_runtime.h>
#include <hip/hip_bf16.h>

typedef __attribute__((ext_vector_type(8))) short s8v;
typedef __attribute__((ext_vector_type(4))) short s4v;
typedef __attribute__((ext_vector_type(4))) float f4v;

#define MFMA32(A,B,C) __builtin_amdgcn_mfma_f32_16x16x32_bf16(A,B,C,0,0,0)
#define MFMA16(A,B,C) __builtin_amdgcn_mfma_f32_16x16x16bf16_1k(A,B,C,0,0,0)

__device__ __forceinline__ unsigned short f2bf(float f){
  unsigned int u = __float_as_uint(f);
  u += 0x7FFFu + ((u>>16)&1u);
  return (unsigned short)(u>>16);
}
__device__ __forceinline__ float bf2f(unsigned short s){
  return __uint_as_float(((unsigned int)s)<<16);
}

// packed f32x4 -> bf16x4 (v_cvt_pk_bf16_f32 on gfx950)
__device__ __forceinline__ s4v pack4(float x, float y, float z, float w){
  s4v r;
#if __has_builtin(__builtin_amdgcn_cvt_pk_bf16_f32)
  typedef __attribute__((ext_vector_type(2))) __bf16 b2;
  b2 lo = __builtin_amdgcn_cvt_pk_bf16_f32(x,y);
  b2 hi = __builtin_amdgcn_cvt_pk_bf16_f32(z,w);
  int2 p;
  __builtin_memcpy(&p.x,&lo,4);
  __builtin_memcpy(&p.y,&hi,4);
  __builtin_memcpy(&r,&p,8);
#else
  r[0]=(short)f2bf(x); r[1]=(short)f2bf(y); r[2]=(short)f2bf(z); r[3]=(short)f2bf(w);
#endif
  return r;
}

// LDS-only barrier: order the ds ops, leave global loads in flight
__device__ __forceinline__ void lds_barrier(){
  asm volatile("s_waitcnt lgkmcnt(0)\n\ts_barrier" ::: "memory");
}

// log2(e)/8  (fold the 1/sqrt(dh)=1/8 score scale into exp2)
#define EXPC 0.18033688011112042f

// ---------------------------------------------------------------------------
// K0: Wo' [o][h*64+j] = Wo[o][j*16+h], bf16
// ---------------------------------------------------------------------------
__global__ void pack_wo(const float* __restrict__ wo, unsigned short* __restrict__ wop){
  int idx = blockIdx.x*256 + threadIdx.x;
  if(idx >= 1024*1024) return;
  int o = idx >> 10, r = idx & 1023, h = r >> 6, j = r & 63;
  wop[idx] = f2bf(wo[o*1024 + j*16 + h]);
}

// ---------------------------------------------------------------------------
// K1: projections. C[m,n] = sum_k A[m,k] * W[n,k] + bias[n]
//   z=0: KEY  -> kh[b][h][s][j]   z=1: QUERY-> qh   z=2: VALUE-> vt[b][h][j][s]
// ---------------------------------------------------------------------------
__global__ __launch_bounds__(256) void proj_gemm(
    const float* __restrict__ KEY, const float* __restrict__ VALUE, const float* __restrict__ QUERY,
    const float* __restrict__ Wk, const float* __restrict__ bk,
    const float* __restrict__ Wq, const float* __restrict__ bq,
    const float* __restrict__ Wv, const float* __restrict__ bv,
    unsigned short* __restrict__ kh, unsigned short* __restrict__ qh,
    unsigned short* __restrict__ vt)
{
  __shared__ short As[128*64];
  __shared__ short Bs[128*64];
  const int t = threadIdx.x;
  const int z = blockIdx.z;
  const float* A; const float* W; const float* bias;
  if(z==0){A=KEY;   W=Wk; bias=bk;}
  else if(z==1){A=QUERY; W=Wq; bias=bq;}
  else {A=VALUE; W=Wv; bias=bv;}
  const int m0 = blockIdx.x*128, n0 = blockIdx.y*128;
  const int l = t&63, w = t>>6;
  const int wm = (w>>1)*64, wn = (w&1)*64;
  const int row16 = l&15, quad = l>>4;
  f4v acc[4][4];
  #pragma unroll
  for(int i=0;i<4;i++)
    #pragma unroll
    for(int j=0;j<4;j++) acc[i][j] = (f4v){0.f,0.f,0.f,0.f};

  const int sr = t>>4, sc = t&15;
  for(int k0=0;k0<1024;k0+=64){
    #pragma unroll
    for(int p=0;p<8;p++){
      float4 av = *(const float4*)&A[(size_t)(m0 + p*16 + sr)*1024 + k0 + sc*4];
      float4 bvv= *(const float4*)&W[(size_t)(n0 + p*16 + sr)*1024 + k0 + sc*4];
      *(s4v*)&As[(p*16+sr)*64 + sc*4] = pack4(av.x,av.y,av.z,av.w);
      *(s4v*)&Bs[(p*16+sr)*64 + sc*4] = pack4(bvv.x,bvv.y,bvv.z,bvv.w);
    }
    __syncthreads();
    #pragma unroll
    for(int kk=0; kk<64; kk+=32){
      s8v af[4], bf[4];
      #pragma unroll
      for(int mt=0;mt<4;mt++) af[mt] = *(const s8v*)&As[(wm+mt*16+row16)*64 + kk + quad*8];
      #pragma unroll
      for(int nt=0;nt<4;nt++) bf[nt] = *(const s8v*)&Bs[(wn+nt*16+row16)*64 + kk + quad*8];
      #pragma unroll
      for(int mt=0;mt<4;mt++)
        #pragma unroll
        for(int nt=0;nt<4;nt++)
          acc[mt][nt] = MFMA32(af[mt], bf[nt], acc[mt][nt]);
    }
    __syncthreads();
  }

  #pragma unroll
  for(int nt=0;nt<4;nt++){
    const int n = n0 + wn + nt*16 + row16;
    const float bias_n = bias[n];
    const int hh = n & 15;
    const int jj2 = n >> 4;
    #pragma unroll
    for(int mt=0;mt<4;mt++){
      #pragma unroll
      for(int r=0;r<4;r++){
        const int m = m0 + wm + mt*16 + quad*4 + r;
        const float val = acc[mt][nt][r] + bias_n;
        const int bb = m>>11, ss = m&2047;
        if(z==2)
          vt[(size_t)((bb*16+hh)*64 + jj2)*2048 + ss] = f2bf(val);
        else if(z==0)
          kh[(size_t)((bb*16+hh)*2048 + ss)*64 + jj2] = f2bf(val);
        else
          qh[(size_t)((bb*16+hh)*2048 + ss)*64 + jj2] = f2bf(val);
      }
    }
  }
}

// ---------------------------------------------------------------------------
// K2: fused head-softmax attention.
// Block: 8 waves = qg(2) x hg(4); q-tile 32, all 16 heads, i-chunk 512.
// Grid: 512 blocks 1D; (b,ih) = blockIdx & 7 so each XCD (blockIdx%8) owns one
// 4MB K/V working set -> per-XCD L2 reuse. 2 blocks/CU (VGPR<=128).
// Denominator exchange: parity double-buffered LDS + lgkm-only barrier.
// P stays in registers (MFMA C-layout == MFMA16 B-fragment layout).
// ---------------------------------------------------------------------------
__global__ __launch_bounds__(512,4) void fused_attn(
    const unsigned short* __restrict__ kh, const unsigned short* __restrict__ qh,
    const unsigned short* __restrict__ vt, unsigned short* __restrict__ opart)
{
  __shared__ f4v dpart[2][2][4][2][64];   // [parity][qg][hg][sub][lane] = 32 KB
  const int t=threadIdx.x, l=t&63, w=t>>6;
  const int qg=w>>2, hg=w&3;
  const int row16=l&15, quad=l>>4;
  const int flat = blockIdx.x;
  const int comb = flat & 7;          // == ih*2 + b, pinned to XCD flat%8
  const int qb   = flat >> 3;         // 0..63
  const int b    = comb & 1;
  const int ih   = comb >> 1;         // 0..3
  const int ibase = ih*512;
  const int q0 = qb*32 + qg*16;
  const int h0 = hg*4;

  // strides between consecutive heads: 2048*64 = 131072 elements (both kh and vt)
  const unsigned short* qp0 = &qh[(size_t)((b*16+h0)*2048 + q0 + row16)*64];
  const unsigned short* kb0 = &kh[(size_t)((b*16+h0)*2048 + ibase + row16)*64];
  const unsigned short* vb0 = &vt[(size_t)((b*16+h0)*64 + row16)*2048 + ibase];

  s8v qf[4][2];
  #pragma unroll
  for(int hh=0;hh<4;hh++){
    const unsigned short* qp = qp0 + (size_t)hh*131072;
    qf[hh][0] = *(const s8v*)&qp[quad*8];
    qf[hh][1] = *(const s8v*)&qp[32+quad*8];
  }
  f4v o[4][4];
  #pragma unroll
  for(int i=0;i<4;i++)
    #pragma unroll
    for(int j=0;j<4;j++) o[i][j] = (f4v){0.f,0.f,0.f,0.f};

  for(int i0=0;i0<512;i0+=32){
    f4v e0[4], e1[4];
    #pragma unroll
    for(int hh=0;hh<4;hh++){
      const unsigned short* kp = kb0 + (size_t)hh*131072 + (size_t)i0*64;
      f4v S0 = (f4v){0.f,0.f,0.f,0.f};
      f4v S1 = (f4v){0.f,0.f,0.f,0.f};
      S0 = MFMA32(*(const s8v*)&kp[quad*8],         qf[hh][0], S0);
      S0 = MFMA32(*(const s8v*)&kp[32+quad*8],      qf[hh][1], S0);
      S1 = MFMA32(*(const s8v*)&kp[1024+quad*8],    qf[hh][0], S1);
      S1 = MFMA32(*(const s8v*)&kp[1024+32+quad*8], qf[hh][1], S1);
      #pragma unroll
      for(int r=0;r<4;r++){
        e0[hh][r] = __builtin_amdgcn_exp2f(S0[r]*EXPC);
        e1[hh][r] = __builtin_amdgcn_exp2f(S1[r]*EXPC);
      }
    }
    f4v d0 = (e0[0]+e0[1])+(e0[2]+e0[3]);
    f4v d1 = (e1[0]+e1[1])+(e1[2]+e1[3]);
    const int par = (i0>>5)&1;
    dpart[par][qg][hg][0][l] = d0;
    dpart[par][qg][hg][1][l] = d1;
    lds_barrier();
    f4v s0 = (dpart[par][qg][0][0][l]+dpart[par][qg][1][0][l])
           + (dpart[par][qg][2][0][l]+dpart[par][qg][3][0][l]);
    f4v s1 = (dpart[par][qg][0][1][l]+dpart[par][qg][1][1][l])
           + (dpart[par][qg][2][1][l]+dpart[par][qg][3][1][l]);
    f4v r0, r1;
    #pragma unroll
    for(int r=0;r<4;r++){
      r0[r] = __builtin_amdgcn_rcpf(s0[r]);
      r1[r] = __builtin_amdgcn_rcpf(s1[r]);
    }
    s4v p0[4], p1[4];
    #pragma unroll
    for(int hh=0;hh<4;hh++){
      p0[hh] = pack4(e0[hh][0]*r0[0], e0[hh][1]*r0[1], e0[hh][2]*r0[2], e0[hh][3]*r0[3]);
      p1[hh] = pack4(e1[hh][0]*r1[0], e1[hh][1]*r1[1], e1[hh][2]*r1[2], e1[hh][3]*r1[3]);
    }
    #pragma unroll
    for(int hh=0;hh<4;hh++){
      const unsigned short* vbh = vb0 + (size_t)hh*131072 + i0;
      #pragma unroll
      for(int jt=0;jt<4;jt++){
        const unsigned short* vp = vbh + (size_t)jt*16*2048;
        s4v v0 = *(const s4v*)&vp[quad*4];
        s4v v1 = *(const s4v*)&vp[16+quad*4];
        o[hh][jt] = MFMA16(v0, p0[hh], o[hh][jt]);
        o[hh][jt] = MFMA16(v1, p1[hh], o[hh][jt]);
      }
    }
  }
  // opart[ih][b*2048+q][1024], ih-stride 4194304 elems
  unsigned short* ob = &opart[(size_t)ih*4194304 + ((size_t)(b*2048 + q0+row16))*1024 + h0*64 + quad*4];
  #pragma unroll
  for(int hh=0;hh<4;hh++){
    #pragma unroll
    for(int jt=0;jt<4;jt++)
      *(s4v*)&ob[hh*64 + jt*16] = pack4(o[hh][jt][0],o[hh][jt][1],o[hh][jt][2],o[hh][jt][3]);
  }
}

// ---------------------------------------------------------------------------
// K3: reduce the 4 i-chunk partials -> out2 bf16
// ---------------------------------------------------------------------------
__global__ __launch_bounds__(256) void reduce_o(
    const unsigned short* __restrict__ op, unsigned short* __restrict__ out2)
{
  size_t e = ((size_t)blockIdx.x*256 + threadIdx.x)*8;
  float s[8];
  #pragma unroll
  for(int i=0;i<8;i++) s[i]=0.f;
  #pragma unroll
  for(int p=0;p<4;p++){
    s8v a = *(const s8v*)&op[(size_t)p*4194304 + e];
    #pragma unroll
    for(int i=0;i<8;i++) s[i] += bf2f((unsigned short)a[i]);
  }
  s4v lo = pack4(s[0],s[1],s[2],s[3]);
  s4v hi = pack4(s[4],s[5],s[6],s[7]);
  s8v r;
  #pragma unroll
  for(int i=0;i<4;i++){ r[i] = lo[i]; r[i+4] = hi[i]; }
  *(s8v*)&out2[e] = r;
}

// ---------------------------------------------------------------------------
// K4: res[m][n] = sum_k out2[m,k]*WoP[n,k] + bo[n], fp32 out
// ---------------------------------------------------------------------------
__global__ __launch_bounds__(256) void out_gemm(
    const unsigned short* __restrict__ A, const unsigned short* __restrict__ Bm,
    const float* __restrict__ bias, float* __restrict__ out)
{
  __shared__ short As[128*64];
  __shared__ short Bs[128*64];
  const int t=threadIdx.x, l=t&63, w=t>>6;
  const int row16=l&15, quad=l>>4;
  const int m0=blockIdx.x*128, n0=blockIdx.y*128;
  const int wm=(w>>1)*64, wn=(w&1)*64;
  f4v acc[4][4];
  #pragma unroll
  for(int i=0;i<4;i++)
    #pragma unroll
    for(int j=0;j<4;j++) acc[i][j] = (f4v){0.f,0.f,0.f,0.f};

  const int sr=t>>3, sc=(t&7)*8;
  for(int k0=0;k0<1024;k0+=64){
    #pragma unroll
    for(int p=0;p<4;p++){
      *(s8v*)&As[(p*32+sr)*64 + sc] = *(const s8v*)&A [(size_t)(m0+p*32+sr)*1024 + k0 + sc];
      *(s8v*)&Bs[(p*32+sr)*64 + sc] = *(const s8v*)&Bm[(size_t)(n0+p*32+sr)*1024 + k0 + sc];
    }
    __syncthreads();
    #pragma unroll
    for(int kk=0; kk<64; kk+=32){
      s8v af[4], bf[4];
      #pragma unroll
      for(int mt=0;mt<4;mt++) af[mt] = *(const s8v*)&As[(wm+mt*16+row16)*64 + kk + quad*8];
      #pragma unroll
      for(int nt=0;nt<4;nt++) bf[nt] = *(const s8v*)&Bs[(wn+nt*16+row16)*64 + kk + quad*8];
      #pragma unroll
      for(int mt=0;mt<4;mt++)
        #pragma unroll
        for(int nt=0;nt<4;nt++)
          acc[mt][nt] = MFMA32(af[mt], bf[nt], acc[mt][nt]);
    }
    __syncthreads();
  }
  #pragma unroll
  for(int nt=0;nt<4;nt++){
    const int n = n0+wn+nt*16+row16;
    const float bias_n = bias[n];
    #pragma unroll
    for(int mt=0;mt<4;mt++)
      #pragma unroll
      for(int r=0;r<4;r++){
        const int m = m0+wm+mt*16+quad*4+r;
        out[(size_t)m*1024 + n] = acc[mt][nt][r] + bias_n;
      }
  }
}

// ---------------------------------------------------------------------------
extern "C" void kernel_launch(void* const* d_in, const int* in_sizes, int n_in,
                              void* d_out, int out_size, void* d_ws, size_t ws_size,
                              hipStream_t stream)
{
  const float* KEY   = (const float*)d_in[0];
  const float* VALUE = (const float*)d_in[1];
  const float* QUERY = (const float*)d_in[2];
  const float* Wk = (const float*)d_in[3];
  const float* bk = (const float*)d_in[4];
  const float* Wq = (const float*)d_in[5];
  const float* bq = (const float*)d_in[6];
  const float* Wv = (const float*)d_in[7];
  const float* bv = (const float*)d_in[8];
  const float* Wo = (const float*)d_in[9];
  const float* bo = (const float*)d_in[10];

  char* ws = (char*)d_ws;
  unsigned short* kh   = (unsigned short*)(ws);                 //  8 MiB [2][16][2048][64]
  unsigned short* qh   = (unsigned short*)(ws +  8388608);      //  8 MiB
  unsigned short* vt   = (unsigned short*)(ws + 16777216);      //  8 MiB [2][16][64][2048]
  unsigned short* wop  = (unsigned short*)(ws + 25165824);      //  2 MiB
  unsigned short* opart= (unsigned short*)(ws + 27262976);      // 32 MiB [4ih][4096][1024]
  unsigned short* out2 = (unsigned short*)(ws);                 //  aliases kh (dead by reduce_o)

  pack_wo   <<<dim3(4096),   dim3(256), 0, stream>>>(Wo, wop);
  proj_gemm <<<dim3(32,8,3), dim3(256), 0, stream>>>(KEY,VALUE,QUERY,Wk,bk,Wq,bq,Wv,bv,kh,qh,vt);
  fused_attn<<<dim3(512),    dim3(512), 0, stream>>>(kh,qh,vt,opart);
  reduce_o  <<<dim3(2048),   dim3(256), 0, stream>>>(opart,out2);
  out_gemm  <<<dim3(32,8),   dim3(256), 0, stream>>>(out2,wop,bo,(float*)d_out);
}

// Round 5
// 636.638 us; speedup vs baseline: 1.0848x; 1.0848x over previous
//
#include <hip/hip_runtime.h>
#include <hip/hip_bf16.h>

typedef __attribute__((ext_vector_type(8))) short s8v;
typedef __attribute__((ext_vector_type(4))) short s4v;
typedef __attribute__((ext_vector_type(4))) float f4v;

#define MFMA32(A,B,C) __builtin_amdgcn_mfma_f32_16x16x32_bf16(A,B,C,0,0,0)
#define MFMA16(A,B,C) __builtin_amdgcn_mfma_f32_16x16x16bf16_1k(A,B,C,0,0,0)

__device__ __forceinline__ unsigned short f2bf(float f){
  unsigned int u = __float_as_uint(f);
  u += 0x7FFFu + ((u>>16)&1u);
  return (unsigned short)(u>>16);
}
__device__ __forceinline__ float bf2f(unsigned short s){
  return __uint_as_float(((unsigned int)s)<<16);
}

// packed f32x4 -> bf16x4 (v_cvt_pk_bf16_f32 on gfx950)
__device__ __forceinline__ s4v pack4(float x, float y, float z, float w){
  s4v r;
#if __has_builtin(__builtin_amdgcn_cvt_pk_bf16_f32)
  typedef __attribute__((ext_vector_type(2))) __bf16 b2;
  b2 lo = __builtin_amdgcn_cvt_pk_bf16_f32(x,y);
  b2 hi = __builtin_amdgcn_cvt_pk_bf16_f32(z,w);
  int2 p;
  __builtin_memcpy(&p.x,&lo,4);
  __builtin_memcpy(&p.y,&hi,4);
  __builtin_memcpy(&r,&p,8);
#else
  r[0]=(short)f2bf(x); r[1]=(short)f2bf(y); r[2]=(short)f2bf(z); r[3]=(short)f2bf(w);
#endif
  return r;
}

// LDS-only barrier: order the ds ops, leave global loads in flight
__device__ __forceinline__ void lds_barrier(){
  asm volatile("s_waitcnt lgkmcnt(0)\n\ts_barrier" ::: "memory");
}

// log2(e)/8  (fold the 1/sqrt(dh)=1/8 score scale into exp2)
#define EXPC 0.18033688011112042f

// ---------------------------------------------------------------------------
// K0: Wo' [o][h*64+j] = Wo[o][j*16+h], bf16
// ---------------------------------------------------------------------------
__global__ void pack_wo(const float* __restrict__ wo, unsigned short* __restrict__ wop){
  int idx = blockIdx.x*256 + threadIdx.x;
  if(idx >= 1024*1024) return;
  int o = idx >> 10, r = idx & 1023, h = r >> 6, j = r & 63;
  wop[idx] = f2bf(wo[o*1024 + j*16 + h]);
}

// ---------------------------------------------------------------------------
// K1: projections. C[m,n] = sum_k A[m,k] * W[n,k] + bias[n]
//   z=0: KEY  -> kh[b][h][s][j]   z=1: QUERY-> qh   z=2: VALUE-> vt[b][h][j][s]
// ---------------------------------------------------------------------------
__global__ __launch_bounds__(256) void proj_gemm(
    const float* __restrict__ KEY, const float* __restrict__ VALUE, const float* __restrict__ QUERY,
    const float* __restrict__ Wk, const float* __restrict__ bk,
    const float* __restrict__ Wq, const float* __restrict__ bq,
    const float* __restrict__ Wv, const float* __restrict__ bv,
    unsigned short* __restrict__ kh, unsigned short* __restrict__ qh,
    unsigned short* __restrict__ vt)
{
  __shared__ short As[128*64];
  __shared__ short Bs[128*64];
  const int t = threadIdx.x;
  const int z = blockIdx.z;
  const float* A; const float* W; const float* bias;
  if(z==0){A=KEY;   W=Wk; bias=bk;}
  else if(z==1){A=QUERY; W=Wq; bias=bq;}
  else {A=VALUE; W=Wv; bias=bv;}
  const int m0 = blockIdx.x*128, n0 = blockIdx.y*128;
  const int l = t&63, w = t>>6;
  const int wm = (w>>1)*64, wn = (w&1)*64;
  const int row16 = l&15, quad = l>>4;
  f4v acc[4][4];
  #pragma unroll
  for(int i=0;i<4;i++)
    #pragma unroll
    for(int j=0;j<4;j++) acc[i][j] = (f4v){0.f,0.f,0.f,0.f};

  const int sr = t>>4, sc = t&15;
  for(int k0=0;k0<1024;k0+=64){
    #pragma unroll
    for(int p=0;p<8;p++){
      float4 av = *(const float4*)&A[(size_t)(m0 + p*16 + sr)*1024 + k0 + sc*4];
      float4 bvv= *(const float4*)&W[(size_t)(n0 + p*16 + sr)*1024 + k0 + sc*4];
      *(s4v*)&As[(p*16+sr)*64 + sc*4] = pack4(av.x,av.y,av.z,av.w);
      *(s4v*)&Bs[(p*16+sr)*64 + sc*4] = pack4(bvv.x,bvv.y,bvv.z,bvv.w);
    }
    __syncthreads();
    #pragma unroll
    for(int kk=0; kk<64; kk+=32){
      s8v af[4], bf[4];
      #pragma unroll
      for(int mt=0;mt<4;mt++) af[mt] = *(const s8v*)&As[(wm+mt*16+row16)*64 + kk + quad*8];
      #pragma unroll
      for(int nt=0;nt<4;nt++) bf[nt] = *(const s8v*)&Bs[(wn+nt*16+row16)*64 + kk + quad*8];
      #pragma unroll
      for(int mt=0;mt<4;mt++)
        #pragma unroll
        for(int nt=0;nt<4;nt++)
          acc[mt][nt] = MFMA32(af[mt], bf[nt], acc[mt][nt]);
    }
    __syncthreads();
  }

  #pragma unroll
  for(int nt=0;nt<4;nt++){
    const int n = n0 + wn + nt*16 + row16;
    const float bias_n = bias[n];
    const int hh = n & 15;
    const int jj2 = n >> 4;
    #pragma unroll
    for(int mt=0;mt<4;mt++){
      #pragma unroll
      for(int r=0;r<4;r++){
        const int m = m0 + wm + mt*16 + quad*4 + r;
        const float val = acc[mt][nt][r] + bias_n;
        const int bb = m>>11, ss = m&2047;
        if(z==2)
          vt[(size_t)((bb*16+hh)*64 + jj2)*2048 + ss] = f2bf(val);
        else if(z==0)
          kh[(size_t)((bb*16+hh)*2048 + ss)*64 + jj2] = f2bf(val);
        else
          qh[(size_t)((bb*16+hh)*2048 + ss)*64 + jj2] = f2bf(val);
      }
    }
  }
}

// ---------------------------------------------------------------------------
// K2: fused head-softmax attention, THIN-WAVE layout.
// Block: 8 waves = 8 head-groups x 2 heads (all 16 heads -> head-softmax
// coupling stays in-block); q-tile 16 per block; i-chunk 512.
// Per-lane state: o[2][4]=32 acc + qf 16 + temps -> ~120 total regs, so
// 4 waves/SIMD fit WITHOUT forcing (launch_bounds cap 170 only guards
// against ballooning; R3 showed forcing 128 => scratch spill disaster).
// Grid: 1024 blocks; comb=blockIdx&7 pins (b,ih) to an XCD for L2 reuse.
// Denominator exchange: parity double-buffered LDS + lgkm-only barrier.
// P stays in registers (MFMA C-layout == MFMA16 B-fragment layout).
// ---------------------------------------------------------------------------
__global__ __launch_bounds__(512,3) void fused_attn(
    const unsigned short* __restrict__ kh, const unsigned short* __restrict__ qh,
    const unsigned short* __restrict__ vt, unsigned short* __restrict__ opart)
{
  __shared__ f4v dpart[2][8][2][64];   // [parity][hg][sub][lane] = 32 KB
  const int t=threadIdx.x, l=t&63, hg=t>>6;
  const int row16=l&15, quad=l>>4;
  const int flat = blockIdx.x;
  const int comb = flat & 7;          // == ih*2 + b, pinned to XCD flat%8
  const int qb   = flat >> 3;         // 0..127
  const int b    = comb & 1;
  const int ih   = comb >> 1;         // 0..3
  const int ibase = ih*512;
  const int q0 = qb*16;
  const int h0 = hg*2;

  // stride between consecutive heads: 2048*64 = 131072 elements (kh and vt)
  const unsigned short* qp0 = &qh[(size_t)((b*16+h0)*2048 + q0 + row16)*64];
  const unsigned short* kb0 = &kh[(size_t)((b*16+h0)*2048 + ibase + row16)*64];
  const unsigned short* vb0 = &vt[(size_t)((b*16+h0)*64 + row16)*2048 + ibase];

  s8v qf[2][2];
  #pragma unroll
  for(int hh=0;hh<2;hh++){
    const unsigned short* qp = qp0 + (size_t)hh*131072;
    qf[hh][0] = *(const s8v*)&qp[quad*8];
    qf[hh][1] = *(const s8v*)&qp[32+quad*8];
  }
  f4v o[2][4];
  #pragma unroll
  for(int i=0;i<2;i++)
    #pragma unroll
    for(int j=0;j<4;j++) o[i][j] = (f4v){0.f,0.f,0.f,0.f};

  for(int i0=0;i0<512;i0+=32){
    f4v e0[2], e1[2];
    #pragma unroll
    for(int hh=0;hh<2;hh++){
      const unsigned short* kp = kb0 + (size_t)hh*131072 + (size_t)i0*64;
      f4v S0 = (f4v){0.f,0.f,0.f,0.f};
      f4v S1 = (f4v){0.f,0.f,0.f,0.f};
      S0 = MFMA32(*(const s8v*)&kp[quad*8],         qf[hh][0], S0);
      S0 = MFMA32(*(const s8v*)&kp[32+quad*8],      qf[hh][1], S0);
      S1 = MFMA32(*(const s8v*)&kp[1024+quad*8],    qf[hh][0], S1);
      S1 = MFMA32(*(const s8v*)&kp[1024+32+quad*8], qf[hh][1], S1);
      #pragma unroll
      for(int r=0;r<4;r++){
        e0[hh][r] = __builtin_amdgcn_exp2f(S0[r]*EXPC);
        e1[hh][r] = __builtin_amdgcn_exp2f(S1[r]*EXPC);
      }
    }
    const int par = (i0>>5)&1;
    dpart[par][hg][0][l] = e0[0]+e0[1];
    dpart[par][hg][1][l] = e1[0]+e1[1];
    lds_barrier();
    f4v s0 = ((dpart[par][0][0][l]+dpart[par][1][0][l])
            + (dpart[par][2][0][l]+dpart[par][3][0][l]))
           + ((dpart[par][4][0][l]+dpart[par][5][0][l])
            + (dpart[par][6][0][l]+dpart[par][7][0][l]));
    f4v s1 = ((dpart[par][0][1][l]+dpart[par][1][1][l])
            + (dpart[par][2][1][l]+dpart[par][3][1][l]))
           + ((dpart[par][4][1][l]+dpart[par][5][1][l])
            + (dpart[par][6][1][l]+dpart[par][7][1][l]));
    f4v r0, r1;
    #pragma unroll
    for(int r=0;r<4;r++){
      r0[r] = __builtin_amdgcn_rcpf(s0[r]);
      r1[r] = __builtin_amdgcn_rcpf(s1[r]);
    }
    #pragma unroll
    for(int hh=0;hh<2;hh++){
      s4v p0 = pack4(e0[hh][0]*r0[0], e0[hh][1]*r0[1], e0[hh][2]*r0[2], e0[hh][3]*r0[3]);
      s4v p1 = pack4(e1[hh][0]*r1[0], e1[hh][1]*r1[1], e1[hh][2]*r1[2], e1[hh][3]*r1[3]);
      const unsigned short* vbh = vb0 + (size_t)hh*131072 + i0;
      #pragma unroll
      for(int jt=0;jt<4;jt++){
        const unsigned short* vp = vbh + (size_t)jt*16*2048;
        s4v v0 = *(const s4v*)&vp[quad*4];
        s4v v1 = *(const s4v*)&vp[16+quad*4];
        o[hh][jt] = MFMA16(v0, p0, o[hh][jt]);
        o[hh][jt] = MFMA16(v1, p1, o[hh][jt]);
      }
    }
  }
  // opart[ih][b*2048+q][1024], ih-stride 4194304 elems
  unsigned short* ob = &opart[(size_t)ih*4194304 + ((size_t)(b*2048 + q0+row16))*1024 + h0*64 + quad*4];
  #pragma unroll
  for(int hh=0;hh<2;hh++){
    #pragma unroll
    for(int jt=0;jt<4;jt++)
      *(s4v*)&ob[hh*64 + jt*16] = pack4(o[hh][jt][0],o[hh][jt][1],o[hh][jt][2],o[hh][jt][3]);
  }
}

// ---------------------------------------------------------------------------
// K3: reduce the 4 i-chunk partials -> out2 bf16
// ---------------------------------------------------------------------------
__global__ __launch_bounds__(256) void reduce_o(
    const unsigned short* __restrict__ op, unsigned short* __restrict__ out2)
{
  size_t e = ((size_t)blockIdx.x*256 + threadIdx.x)*8;
  float s[8];
  #pragma unroll
  for(int i=0;i<8;i++) s[i]=0.f;
  #pragma unroll
  for(int p=0;p<4;p++){
    s8v a = *(const s8v*)&op[(size_t)p*4194304 + e];
    #pragma unroll
    for(int i=0;i<8;i++) s[i] += bf2f((unsigned short)a[i]);
  }
  s4v lo = pack4(s[0],s[1],s[2],s[3]);
  s4v hi = pack4(s[4],s[5],s[6],s[7]);
  s8v r;
  #pragma unroll
  for(int i=0;i<4;i++){ r[i] = lo[i]; r[i+4] = hi[i]; }
  *(s8v*)&out2[e] = r;
}

// ---------------------------------------------------------------------------
// K4: res[m][n] = sum_k out2[m,k]*WoP[n,k] + bo[n], fp32 out
// ---------------------------------------------------------------------------
__global__ __launch_bounds__(256) void out_gemm(
    const unsigned short* __restrict__ A, const unsigned short* __restrict__ Bm,
    const float* __restrict__ bias, float* __restrict__ out)
{
  __shared__ short As[128*64];
  __shared__ short Bs[128*64];
  const int t=threadIdx.x, l=t&63, w=t>>6;
  const int row16=l&15, quad=l>>4;
  const int m0=blockIdx.x*128, n0=blockIdx.y*128;
  const int wm=(w>>1)*64, wn=(w&1)*64;
  f4v acc[4][4];
  #pragma unroll
  for(int i=0;i<4;i++)
    #pragma unroll
    for(int j=0;j<4;j++) acc[i][j] = (f4v){0.f,0.f,0.f,0.f};

  const int sr=t>>3, sc=(t&7)*8;
  for(int k0=0;k0<1024;k0+=64){
    #pragma unroll
    for(int p=0;p<4;p++){
      *(s8v*)&As[(p*32+sr)*64 + sc] = *(const s8v*)&A [(size_t)(m0+p*32+sr)*1024 + k0 + sc];
      *(s8v*)&Bs[(p*32+sr)*64 + sc] = *(const s8v*)&Bm[(size_t)(n0+p*32+sr)*1024 + k0 + sc];
    }
    __syncthreads();
    #pragma unroll
    for(int kk=0; kk<64; kk+=32){
      s8v af[4], bf[4];
      #pragma unroll
      for(int mt=0;mt<4;mt++) af[mt] = *(const s8v*)&As[(wm+mt*16+row16)*64 + kk + quad*8];
      #pragma unroll
      for(int nt=0;nt<4;nt++) bf[nt] = *(const s8v*)&Bs[(wn+nt*16+row16)*64 + kk + quad*8];
      #pragma unroll
      for(int mt=0;mt<4;mt++)
        #pragma unroll
        for(int nt=0;nt<4;nt++)
          acc[mt][nt] = MFMA32(af[mt], bf[nt], acc[mt][nt]);
    }
    __syncthreads();
  }
  #pragma unroll
  for(int nt=0;nt<4;nt++){
    const int n = n0+wn+nt*16+row16;
    const float bias_n = bias[n];
    #pragma unroll
    for(int mt=0;mt<4;mt++)
      #pragma unroll
      for(int r=0;r<4;r++){
        const int m = m0+wm+mt*16+quad*4+r;
        out[(size_t)m*1024 + n] = acc[mt][nt][r] + bias_n;
      }
  }
}

// ---------------------------------------------------------------------------
extern "C" void kernel_launch(void* const* d_in, const int* in_sizes, int n_in,
                              void* d_out, int out_size, void* d_ws, size_t ws_size,
                              hipStream_t stream)
{
  const float* KEY   = (const float*)d_in[0];
  const float* VALUE = (const float*)d_in[1];
  const float* QUERY = (const float*)d_in[2];
  const float* Wk = (const float*)d_in[3];
  const float* bk = (const float*)d_in[4];
  const float* Wq = (const float*)d_in[5];
  const float* bq = (const float*)d_in[6];
  const float* Wv = (const float*)d_in[7];
  const float* bv = (const float*)d_in[8];
  const float* Wo = (const float*)d_in[9];
  const float* bo = (const float*)d_in[10];

  char* ws = (char*)d_ws;
  unsigned short* kh   = (unsigned short*)(ws);                 //  8 MiB [2][16][2048][64]
  unsigned short* qh   = (unsigned short*)(ws +  8388608);      //  8 MiB
  unsigned short* vt   = (unsigned short*)(ws + 16777216);      //  8 MiB [2][16][64][2048]
  unsigned short* wop  = (unsigned short*)(ws + 25165824);      //  2 MiB
  unsigned short* opart= (unsigned short*)(ws + 27262976);      // 32 MiB [4ih][4096][1024]
  unsigned short* out2 = (unsigned short*)(ws);                 //  aliases kh (dead by reduce_o)

  pack_wo   <<<dim3(4096),   dim3(256), 0, stream>>>(Wo, wop);
  proj_gemm <<<dim3(32,8,3), dim3(256), 0, stream>>>(KEY,VALUE,QUERY,Wk,bk,Wq,bq,Wv,bv,kh,qh,vt);
  fused_attn<<<dim3(1024),   dim3(512), 0, stream>>>(kh,qh,vt,opart);
  reduce_o  <<<dim3(2048),   dim3(256), 0, stream>>>(opart,out2);
  out_gemm  <<<dim3(32,8),   dim3(256), 0, stream>>>(out2,wop,bo,(float*)d_out);
}